// Round 1
// baseline (369.420 us; speedup 1.0000x reference)
//
#include <hip/hip_runtime.h>
#include <math.h>

#define TSEQ 2048
#define BB 8
#define EE 128
#define HH 4
#define UHN 512   // E*H
#define KTOP 22   // int(3*ln(2048)) = int(22.8739) = 22

__device__ __forceinline__ float2 cmul(float2 a, float2 b) {
  return make_float2(a.x*b.x - a.y*b.y, a.x*b.y + a.y*b.x);
}

// ---------------------------------------------------------------------------
// Stage 1: q/k/v = hs @ W + b, written TRANSPOSED as [b][uh][t] (uh = u*4+h)
// grid (8 uh-tiles, 256 bt-tiles, 3 weights), 256 threads, 64x64 tile, K=128
// ---------------------------------------------------------------------------
__global__ __launch_bounds__(256)
void proj_kernel(const float* __restrict__ hs,
                 const float* __restrict__ wq, const float* __restrict__ bq,
                 const float* __restrict__ wk, const float* __restrict__ bk,
                 const float* __restrict__ wv, const float* __restrict__ bv,
                 float* __restrict__ q_t, float* __restrict__ k_t, float* __restrict__ v_t)
{
  __shared__ __align__(16) float hs_lds[64][65];   // [bt][j] pad->conflict-free strided reads
  __shared__ __align__(16) float w_lds[64][64];    // [j][uh]

  const float* W; const float* bias; float* outp;
  if (blockIdx.z == 0)      { W = wq; bias = bq; outp = q_t; }
  else if (blockIdx.z == 1) { W = wk; bias = bk; outp = k_t; }
  else                      { W = wv; bias = bv; outp = v_t; }

  const int tid = threadIdx.x;
  const int bt0 = blockIdx.y * 64;
  const int uh0 = blockIdx.x * 64;
  const int tt = tid & 15;   // owns t = tt + 16*i
  const int uu = tid >> 4;   // owns uh = uu*4 + m

  float acc[4][4] = {};

  for (int kc = 0; kc < 2; ++kc) {
    __syncthreads();
#pragma unroll
    for (int r = 0; r < 16; ++r) {
      int idx = tid + 256*r;                 // 4096
      int row = idx >> 6, col = idx & 63;
      hs_lds[row][col] = hs[(size_t)(bt0 + row)*EE + kc*64 + col];
    }
#pragma unroll
    for (int r = 0; r < 16; ++r) {
      int idx = tid + 256*r;
      int row = idx >> 6, col = idx & 63;
      w_lds[row][col] = W[(size_t)(kc*64 + row)*UHN + uh0 + col];
    }
    __syncthreads();
#pragma unroll 4
    for (int j = 0; j < 64; ++j) {
      float4 w4 = *(const float4*)&w_lds[j][uu*4];
      float wv_[4] = {w4.x, w4.y, w4.z, w4.w};
      float a_[4]  = { hs_lds[tt][j], hs_lds[tt+16][j],
                       hs_lds[tt+32][j], hs_lds[tt+48][j] };
#pragma unroll
      for (int i = 0; i < 4; ++i)
#pragma unroll
        for (int m = 0; m < 4; ++m)
          acc[i][m] = fmaf(a_[i], wv_[m], acc[i][m]);
    }
  }

  const int b  = bt0 >> 11;          // 64 | 2048 so tile never straddles b
  const int tb = bt0 & (TSEQ - 1);
#pragma unroll
  for (int m = 0; m < 4; ++m) {
    int uh = uh0 + uu*4 + m;
    float bia = bias[uh];
    size_t base = ((size_t)(b*UHN + uh))*TSEQ + tb;
#pragma unroll
    for (int i = 0; i < 4; ++i)
      outp[base + tt + 16*i] = acc[i][m] + bia;
  }
}

// ---------------------------------------------------------------------------
// Stage 2: per (b,u): ac_mean[tau] = (1/(T*H)) * IDFT( sum_h Qf_h * conj(Kf_h) )
// forward DIF (natural -> bitrev), product in bitrev, inverse DIT (bitrev -> natural)
// grid 1024 = (b,u), 256 threads
// ---------------------------------------------------------------------------
__global__ __launch_bounds__(256)
void fftcorr_kernel(const float* __restrict__ q_t, const float* __restrict__ k_t,
                    float* __restrict__ ac)
{
  __shared__ float2 bufQ[TSEQ];
  __shared__ float2 bufK[TSEQ];
  __shared__ float2 Sbuf[TSEQ];
  __shared__ float2 tw[TSEQ/2];    // tw[j] = e^{-2*pi*i*j/2048}

  const int tid = threadIdx.x;
  const int bu  = blockIdx.x;      // b*128 + u

#pragma unroll
  for (int r = 0; r < 4; ++r) {
    int j = tid + 256*r;
    float ang = -6.2831853071795864769f * (float)j / (float)TSEQ;
    float s, c;
    sincosf(ang, &s, &c);
    tw[j] = make_float2(c, s);
  }

  for (int h = 0; h < HH; ++h) {
    const float* qp = q_t + ((size_t)bu*HH + h)*TSEQ;
    const float* kp = k_t + ((size_t)bu*HH + h)*TSEQ;
    __syncthreads();               // prior product done before overwrite
#pragma unroll
    for (int r = 0; r < 8; ++r) {
      int i = tid + 256*r;
      bufQ[i] = make_float2(qp[i], 0.f);
      bufK[i] = make_float2(kp[i], 0.f);
    }
    // forward DIF on both buffers
    int half = 1024, tws = 1;
    for (int st = 0; st < 11; ++st) {
      __syncthreads();
#pragma unroll
      for (int r = 0; r < 4; ++r) {
        int i = tid + 256*r;                 // butterfly id 0..1023
        int j = i & (half - 1);
        int i0 = ((i - j) << 1) + j;
        int i1 = i0 + half;
        float2 w = tw[j * tws];
        float2 a = bufQ[i0], b2 = bufQ[i1];
        bufQ[i0] = make_float2(a.x + b2.x, a.y + b2.y);
        float2 d = make_float2(a.x - b2.x, a.y - b2.y);
        bufQ[i1] = cmul(d, w);
        a = bufK[i0]; b2 = bufK[i1];
        bufK[i0] = make_float2(a.x + b2.x, a.y + b2.y);
        d = make_float2(a.x - b2.x, a.y - b2.y);
        bufK[i1] = cmul(d, w);
      }
      half >>= 1; tws <<= 1;
    }
    __syncthreads();
    // S (+)= Q * conj(K)   (both in bit-reversed order -> fine for pointwise)
#pragma unroll
    for (int r = 0; r < 8; ++r) {
      int i = tid + 256*r;
      float2 qv = bufQ[i], kv = bufK[i];
      float2 p = make_float2(qv.x*kv.x + qv.y*kv.y, qv.y*kv.x - qv.x*kv.y);
      if (h == 0) Sbuf[i] = p;
      else { Sbuf[i].x += p.x; Sbuf[i].y += p.y; }
    }
  }

  // inverse DIT (conjugate twiddles), bitrev input -> natural output
  {
    int half = 1, tws = 1024;
    for (int st = 0; st < 11; ++st) {
      __syncthreads();
#pragma unroll
      for (int r = 0; r < 4; ++r) {
        int i = tid + 256*r;
        int j = i & (half - 1);
        int i0 = ((i - j) << 1) + j;
        int i1 = i0 + half;
        float2 w = tw[j * tws]; w.y = -w.y;
        float2 a = Sbuf[i0], b2 = Sbuf[i1];
        float2 t = cmul(b2, w);
        Sbuf[i0] = make_float2(a.x + t.x, a.y + t.y);
        Sbuf[i1] = make_float2(a.x - t.x, a.y - t.y);
      }
      half <<= 1; tws >>= 1;
    }
  }
  __syncthreads();

  const float scale = 1.0f / (float)(TSEQ * HH);   // irfft 1/T and mean 1/H
#pragma unroll
  for (int r = 0; r < 8; ++r) {
    int i = tid + 256*r;
    ac[(size_t)bu*TSEQ + i] = Sbuf[i].x * scale;
  }
}

// ---------------------------------------------------------------------------
// Stage 3: top-22 over tau per (b,u); keep idx[21] and softmax(vals)[21]
// tie-break: value desc, index asc (matches lax.top_k)
// ---------------------------------------------------------------------------
__global__ __launch_bounds__(256)
void topk_kernel(const float* __restrict__ ac, int* __restrict__ delay,
                 float* __restrict__ wgt)
{
  __shared__ float v[TSEQ];
  __shared__ float rv[4];
  __shared__ int   ri[4];

  const int tid = threadIdx.x;
  const int bu  = blockIdx.x;

#pragma unroll
  for (int r = 0; r < 8; ++r) {
    int i = tid + 256*r;
    v[i] = ac[(size_t)bu*TSEQ + i];
  }

  float m0 = 0.f, ssum = 0.f;   // only thread 0's copies are meaningful
  for (int it = 0; it < KTOP; ++it) {
    __syncthreads();
    float best = -3.4e38f; int bi = 0;
#pragma unroll
    for (int r = 0; r < 8; ++r) {
      int i = tid + 256*r;      // strictly increasing -> earliest idx kept on ties
      float x = v[i];
      if (x > best) { best = x; bi = i; }
    }
#pragma unroll
    for (int off = 32; off > 0; off >>= 1) {
      float ob = __shfl_down(best, off);
      int   oi = __shfl_down(bi, off);
      if (ob > best || (ob == best && oi < bi)) { best = ob; bi = oi; }
    }
    if ((tid & 63) == 0) { rv[tid >> 6] = best; ri[tid >> 6] = bi; }
    __syncthreads();
    if (tid == 0) {
      float gb = rv[0]; int gi = ri[0];
      for (int w2 = 1; w2 < 4; ++w2)
        if (rv[w2] > gb || (rv[w2] == gb && ri[w2] < gi)) { gb = rv[w2]; gi = ri[w2]; }
      v[gi] = -3.4e38f;
      if (it == 0) m0 = gb;
      ssum += expf(gb - m0);
      if (it == KTOP - 1) {
        delay[bu] = gi;
        wgt[bu]   = expf(gb - m0) / ssum;
      }
    }
  }
}

// ---------------------------------------------------------------------------
// Stage 4: out[b,t,f] = sum_uh v[b,(t+delay[b,u])%T,u,h]*wgt[b,u]*wo[uh,f] + bo[f]
// grid (32 t-tiles, 8 b), 256 threads; 64t x 128f tile, uh in 8 chunks of 64
// ---------------------------------------------------------------------------
__global__ __launch_bounds__(256)
void out_kernel(const float* __restrict__ v_t, const int* __restrict__ delay,
                const float* __restrict__ wgt, const float* __restrict__ wo,
                const float* __restrict__ bo, float* __restrict__ out)
{
  __shared__ __align__(16) float rolled[64][64];    // [uh_local][t_local]
  __shared__ __align__(16) float wo_lds[64][128];   // [uh_local][f]
  __shared__ int   dly[EE];
  __shared__ float wg[EE];

  const int tid = threadIdx.x;
  const int b   = blockIdx.y;
  const int t0  = blockIdx.x * 64;
  if (tid < EE) { dly[tid] = delay[b*EE + tid]; wg[tid] = wgt[b*EE + tid]; }

  const int tt = tid & 15;   // t = tt*4 + i
  const int ff = tid >> 4;   // f = ff*8 + j
  float acc[4][8] = {};

  for (int c = 0; c < 8; ++c) {
    __syncthreads();
#pragma unroll
    for (int r = 0; r < 32; ++r) {
      int idx = tid + 256*r;            // 8192
      int row = idx >> 7, col = idx & 127;
      wo_lds[row][col] = wo[(size_t)(c*64 + row)*EE + col];
    }
#pragma unroll
    for (int r = 0; r < 16; ++r) {
      int idx = tid + 256*r;            // 4096
      int uhl = idx >> 6, tl = idx & 63;
      int uh = c*64 + uhl;
      int u  = uh >> 2;
      rolled[uhl][tl] =
        v_t[((size_t)(b*UHN + uh))*TSEQ + ((t0 + tl + dly[u]) & (TSEQ-1))] * wg[u];
    }
    __syncthreads();
#pragma unroll 2
    for (int uhr = 0; uhr < 64; ++uhr) {
      float4 rv4 = *(const float4*)&rolled[uhr][tt*4];
      float4 wa  = *(const float4*)&wo_lds[uhr][ff*8];
      float4 wb  = *(const float4*)&wo_lds[uhr][ff*8 + 4];
      float rr[4] = {rv4.x, rv4.y, rv4.z, rv4.w};
      float ww[8] = {wa.x, wa.y, wa.z, wa.w, wb.x, wb.y, wb.z, wb.w};
#pragma unroll
      for (int i = 0; i < 4; ++i)
#pragma unroll
        for (int j = 0; j < 8; ++j)
          acc[i][j] = fmaf(rr[i], ww[j], acc[i][j]);
    }
  }

#pragma unroll
  for (int i = 0; i < 4; ++i) {
    int t = t0 + tt*4 + i;
    size_t base = ((size_t)(b*TSEQ + t))*EE + ff*8;
    float4 o0 = make_float4(acc[i][0] + bo[ff*8+0], acc[i][1] + bo[ff*8+1],
                            acc[i][2] + bo[ff*8+2], acc[i][3] + bo[ff*8+3]);
    float4 o1 = make_float4(acc[i][4] + bo[ff*8+4], acc[i][5] + bo[ff*8+5],
                            acc[i][6] + bo[ff*8+6], acc[i][7] + bo[ff*8+7]);
    *(float4*)&out[base]     = o0;
    *(float4*)&out[base + 4] = o1;
  }
}

// ---------------------------------------------------------------------------
extern "C" void kernel_launch(void* const* d_in, const int* in_sizes, int n_in,
                              void* d_out, int out_size, void* d_ws, size_t ws_size,
                              hipStream_t stream) {
  (void)in_sizes; (void)n_in; (void)out_size; (void)ws_size;
  const float* hs = (const float*)d_in[0];
  const float* wq = (const float*)d_in[1];
  const float* bq = (const float*)d_in[2];
  const float* wk = (const float*)d_in[3];
  const float* bk = (const float*)d_in[4];
  const float* wv = (const float*)d_in[5];
  const float* bv = (const float*)d_in[6];
  const float* wo = (const float*)d_in[7];
  const float* bo = (const float*)d_in[8];
  float* out = (float*)d_out;

  // workspace layout (floats): q_t|k_t|v_t (8*512*2048 each) | ac (8*128*2048)
  //                            | delay (1024 int) | wgt (1024 f32)  ~= 109 MB
  const size_t NQ = (size_t)BB * UHN * TSEQ;
  float* q_t = (float*)d_ws;
  float* k_t = q_t + NQ;
  float* v_t = k_t + NQ;
  float* ac  = v_t + NQ;
  int*  delay = (int*)(ac + (size_t)BB*EE*TSEQ);
  float* wgt  = (float*)(delay + BB*EE);

  proj_kernel<<<dim3(8, 256, 3), 256, 0, stream>>>(hs, wq, bq, wk, bk, wv, bv,
                                                   q_t, k_t, v_t);
  fftcorr_kernel<<<dim3(1024), 256, 0, stream>>>(q_t, k_t, ac);
  topk_kernel<<<dim3(1024), 256, 0, stream>>>(ac, delay, wgt);
  out_kernel<<<dim3(32, 8), 256, 0, stream>>>(v_t, delay, wgt, wo, bo, out);
}

// Round 2
// 210.528 us; speedup vs baseline: 1.7547x; 1.7547x over previous
//
#include <hip/hip_runtime.h>
#include <math.h>

#define TSEQ 2048
#define BB 8
#define EE 128
#define HH 4
#define UHN 512           // E*H
#define KTOP 22           // int(3*ln(2048))
#define BT (BB*TSEQ)      // 16384

__device__ __forceinline__ float2 cmul(float2 a, float2 b) {
  return make_float2(a.x*b.x - a.y*b.y, a.x*b.y + a.y*b.x);
}

// ---------------------------------------------------------------------------
// Stage 0: hs [16384][128] -> hs_T [128][16384]  (k-major for proj A-tiles)
// ---------------------------------------------------------------------------
__global__ __launch_bounds__(256)
void transpose_hs(const float* __restrict__ hs, float* __restrict__ hs_T)
{
  __shared__ float tile[64][65];
  const int tid = threadIdx.x;
  const int bt0 = blockIdx.x * 64;
  const int k0  = blockIdx.y * 64;
#pragma unroll
  for (int r = 0; r < 16; ++r) {
    int idx = tid + 256*r;
    int row = idx >> 6, col = idx & 63;
    tile[row][col] = hs[(size_t)(bt0 + row)*EE + k0 + col];
  }
  __syncthreads();
#pragma unroll
  for (int r = 0; r < 16; ++r) {
    int idx = tid + 256*r;
    int row = idx >> 6, col = idx & 63;      // row = k-local, col = bt-local
    hs_T[(size_t)(k0 + row)*BT + bt0 + col] = tile[col][row];
  }
}

// ---------------------------------------------------------------------------
// Stage 1: q/k/v = hs @ W + b, transposed out [b][uh][t]
// 128bt x 128uh tile, K=128 in 2 chunks, 8x8 per-thread blocking
// grid (4 uh-tiles, 128 bt-tiles, 3 weights), 256 threads
// ---------------------------------------------------------------------------
__global__ __launch_bounds__(256)
void proj_kernel(const float* __restrict__ hs_T,
                 const float* __restrict__ wq, const float* __restrict__ bq,
                 const float* __restrict__ wk, const float* __restrict__ bk,
                 const float* __restrict__ wv, const float* __restrict__ bv,
                 float* __restrict__ q_t, float* __restrict__ k_t, float* __restrict__ v_t)
{
  __shared__ __align__(16) float a_lds[64][128];   // [k][t]
  __shared__ __align__(16) float w_lds[64][128];   // [k][uh]

  const float* W; const float* bias; float* outp;
  if (blockIdx.z == 0)      { W = wq; bias = bq; outp = q_t; }
  else if (blockIdx.z == 1) { W = wk; bias = bk; outp = k_t; }
  else                      { W = wv; bias = bv; outp = v_t; }

  const int tid = threadIdx.x;
  const int bt0 = blockIdx.y * 128;
  const int uh0 = blockIdx.x * 128;
  const int tt = tid & 15;    // t = ia*64 + tt*4 + i
  const int ff = tid >> 4;    // uh = jb*64 + ff*4 + j

  float acc[8][8] = {};

  for (int kc = 0; kc < 2; ++kc) {
    __syncthreads();
#pragma unroll
    for (int r = 0; r < 8; ++r) {
      int idx4 = tid + 256*r;                 // 2048 float4s per buffer
      int krow = idx4 >> 5, col4 = (idx4 & 31) << 2;
      *(float4*)&a_lds[krow][col4] =
        *(const float4*)&hs_T[(size_t)(kc*64 + krow)*BT + bt0 + col4];
      *(float4*)&w_lds[krow][col4] =
        *(const float4*)&W[(size_t)(kc*64 + krow)*UHN + uh0 + col4];
    }
    __syncthreads();
#pragma unroll 2
    for (int k = 0; k < 64; ++k) {
      float4 a0 = *(const float4*)&a_lds[k][tt*4];
      float4 a1 = *(const float4*)&a_lds[k][tt*4 + 64];
      float4 w0 = *(const float4*)&w_lds[k][ff*4];
      float4 w1 = *(const float4*)&w_lds[k][ff*4 + 64];
      float av[8] = {a0.x,a0.y,a0.z,a0.w, a1.x,a1.y,a1.z,a1.w};
      float wv_[8] = {w0.x,w0.y,w0.z,w0.w, w1.x,w1.y,w1.z,w1.w};
#pragma unroll
      for (int ti = 0; ti < 8; ++ti)
#pragma unroll
        for (int fj = 0; fj < 8; ++fj)
          acc[ti][fj] = fmaf(av[ti], wv_[fj], acc[ti][fj]);
    }
  }

  const int b   = bt0 >> 11;
  const int t00 = bt0 & (TSEQ - 1);
#pragma unroll
  for (int jb = 0; jb < 2; ++jb)
#pragma unroll
    for (int j = 0; j < 4; ++j) {
      int uh = uh0 + jb*64 + ff*4 + j;
      float bia = bias[uh];
      size_t base = ((size_t)(b*UHN + uh))*TSEQ + t00;
#pragma unroll
      for (int ia = 0; ia < 2; ++ia) {
        float4 o = make_float4(acc[ia*4+0][jb*4+j] + bia, acc[ia*4+1][jb*4+j] + bia,
                               acc[ia*4+2][jb*4+j] + bia, acc[ia*4+3][jb*4+j] + bia);
        *(float4*)&outp[base + ia*64 + tt*4] = o;
      }
    }
}

// ---------------------------------------------------------------------------
// Stage 2: per (b,u): ac = (1/(T*H)) IDFT( sum_h Q_h conj(K_h) )
// packed: one complex FFT of z = q + i*k per h; unpack+multiply in bitrev
// order via partner pp = brev11(N - brev11(p)).
// ---------------------------------------------------------------------------
__device__ __forceinline__ int brev11(int x) { return (int)(__brev((unsigned)x) >> 21); }

__global__ __launch_bounds__(256)
void fftcorr_kernel(const float* __restrict__ q_t, const float* __restrict__ k_t,
                    float* __restrict__ ac)
{
  __shared__ float2 bufZ[TSEQ];
  __shared__ float2 Sbuf[TSEQ];
  __shared__ float2 tw[TSEQ/2];    // tw[j] = e^{-2*pi*i*j/2048}

  const int tid = threadIdx.x;
  const int bu  = blockIdx.x;      // b*128 + u

#pragma unroll
  for (int r = 0; r < 4; ++r) {
    int j = tid + 256*r;
    float ang = -6.2831853071795864769f * (float)j / (float)TSEQ;
    float s, c;
    sincosf(ang, &s, &c);
    tw[j] = make_float2(c, s);
  }

  for (int h = 0; h < HH; ++h) {
    const float* qp = q_t + ((size_t)bu*HH + h)*TSEQ;
    const float* kp = k_t + ((size_t)bu*HH + h)*TSEQ;
    __syncthreads();               // prior product reads done before overwrite
#pragma unroll
    for (int r = 0; r < 8; ++r) {
      int i = tid + 256*r;
      bufZ[i] = make_float2(qp[i], kp[i]);
    }
    // forward DIF: natural -> bit-reversed
    int half = 1024, tws = 1;
    for (int st = 0; st < 11; ++st) {
      __syncthreads();
#pragma unroll
      for (int r = 0; r < 4; ++r) {
        int i = tid + 256*r;                 // butterfly id 0..1023
        int j = i & (half - 1);
        int i0 = ((i - j) << 1) + j;
        int i1 = i0 + half;
        float2 w = tw[j * tws];
        float2 a = bufZ[i0], b2 = bufZ[i1];
        bufZ[i0] = make_float2(a.x + b2.x, a.y + b2.y);
        float2 d = make_float2(a.x - b2.x, a.y - b2.y);
        bufZ[i1] = cmul(d, w);
      }
      half >>= 1; tws <<= 1;
    }
    __syncthreads();
    // unpack Q,K from packed Z and accumulate S += Q * conj(K), in bitrev order
#pragma unroll
    for (int r = 0; r < 8; ++r) {
      int p = tid + 256*r;
      int kfreq = brev11(p);
      int pp = brev11((TSEQ - kfreq) & (TSEQ - 1));
      float2 A  = bufZ[p];
      float2 Zp = bufZ[pp];
      float re = 0.5f  * (Zp.x*A.y + Zp.y*A.x);
      float im = 0.25f * ((A.x*A.x + A.y*A.y) - (Zp.x*Zp.x + Zp.y*Zp.y));
      if (h == 0) Sbuf[p] = make_float2(re, im);
      else { Sbuf[p].x += re; Sbuf[p].y += im; }
    }
  }

  // inverse DIT (conjugate twiddles), bitrev input -> natural output
  {
    int half = 1, tws = 1024;
    for (int st = 0; st < 11; ++st) {
      __syncthreads();
#pragma unroll
      for (int r = 0; r < 4; ++r) {
        int i = tid + 256*r;
        int j = i & (half - 1);
        int i0 = ((i - j) << 1) + j;
        int i1 = i0 + half;
        float2 w = tw[j * tws]; w.y = -w.y;
        float2 a = Sbuf[i0], b2 = Sbuf[i1];
        float2 t = cmul(b2, w);
        Sbuf[i0] = make_float2(a.x + t.x, a.y + t.y);
        Sbuf[i1] = make_float2(a.x - t.x, a.y - t.y);
      }
      half <<= 1; tws >>= 1;
    }
  }
  __syncthreads();

  const float scale = 1.0f / (float)(TSEQ * HH);
#pragma unroll
  for (int r = 0; r < 8; ++r) {
    int i = tid + 256*r;
    ac[(size_t)bu*TSEQ + i] = Sbuf[i].x * scale;
  }
}

// ---------------------------------------------------------------------------
// Stage 3: top-22 per (b,u); keep idx[21], softmax(vals)[21]
// ---------------------------------------------------------------------------
__global__ __launch_bounds__(256)
void topk_kernel(const float* __restrict__ ac, int* __restrict__ delay,
                 float* __restrict__ wgt)
{
  __shared__ float v[TSEQ];
  __shared__ float rv[4];
  __shared__ int   ri[4];

  const int tid = threadIdx.x;
  const int bu  = blockIdx.x;

#pragma unroll
  for (int r = 0; r < 8; ++r) {
    int i = tid + 256*r;
    v[i] = ac[(size_t)bu*TSEQ + i];
  }

  float m0 = 0.f, ssum = 0.f;   // only thread 0's copies matter
  for (int it = 0; it < KTOP; ++it) {
    __syncthreads();
    float best = -3.4e38f; int bi = 0;
#pragma unroll
    for (int r = 0; r < 8; ++r) {
      int i = tid + 256*r;      // increasing -> earliest idx kept on ties
      float x = v[i];
      if (x > best) { best = x; bi = i; }
    }
#pragma unroll
    for (int off = 32; off > 0; off >>= 1) {
      float ob = __shfl_down(best, off);
      int   oi = __shfl_down(bi, off);
      if (ob > best || (ob == best && oi < bi)) { best = ob; bi = oi; }
    }
    if ((tid & 63) == 0) { rv[tid >> 6] = best; ri[tid >> 6] = bi; }
    __syncthreads();
    if (tid == 0) {
      float gb = rv[0]; int gi = ri[0];
      for (int w2 = 1; w2 < 4; ++w2)
        if (rv[w2] > gb || (rv[w2] == gb && ri[w2] < gi)) { gb = rv[w2]; gi = ri[w2]; }
      v[gi] = -3.4e38f;
      if (it == 0) m0 = gb;
      ssum += expf(gb - m0);
      if (it == KTOP - 1) {
        delay[bu] = gi;
        wgt[bu]   = expf(gb - m0) / ssum;
      }
    }
  }
}

// ---------------------------------------------------------------------------
// Stage 4a: partial[ks][bt][f] = sum_{uh in ks-slice} rolled_v * wgt * wo
// grid (128 bt-tiles, 4 ksplit), 256 thr; 128t x 128f, uh chunk 64, 8x8 block
// ---------------------------------------------------------------------------
__global__ __launch_bounds__(256)
void outp_kernel(const float* __restrict__ v_t, const int* __restrict__ delay,
                 const float* __restrict__ wgt, const float* __restrict__ wo,
                 float* __restrict__ partial)
{
  __shared__ __align__(16) float rolled[64][128];   // [uh_local][t_local]
  __shared__ __align__(16) float wo_lds[64][128];   // [uh_local][f]
  __shared__ int   dly_s[32];
  __shared__ float wg_s[32];

  const int tid = threadIdx.x;
  const int mt  = blockIdx.x;
  const int ks  = blockIdx.y;
  const int b   = (mt*128) >> 11;
  const int t0  = (mt*128) & (TSEQ - 1);
  if (tid < 32) {
    dly_s[tid] = delay[b*EE + ks*32 + tid];
    wg_s[tid]  = wgt[b*EE + ks*32 + tid];
  }

  const int tt = tid & 15;   // t = ia*64 + tt*4 + i
  const int ff = tid >> 4;   // f = jb*64 + ff*4 + j
  float acc[8][8] = {};

  for (int c = 0; c < 2; ++c) {
    const int uh0 = ks*128 + c*64;
    __syncthreads();
#pragma unroll
    for (int r = 0; r < 8; ++r) {
      int idx4 = tid + 256*r;
      int row = idx4 >> 5, col4 = (idx4 & 31) << 2;
      *(float4*)&wo_lds[row][col4] = *(const float4*)&wo[(size_t)(uh0 + row)*EE + col4];
    }
#pragma unroll
    for (int r = 0; r < 32; ++r) {
      int idx = tid + 256*r;            // 8192
      int row = idx >> 7, col = idx & 127;
      int ul = (c*64 + row) >> 2;
      rolled[row][col] =
        v_t[((size_t)(b*UHN + uh0 + row))*TSEQ + ((t0 + col + dly_s[ul]) & (TSEQ-1))]
        * wg_s[ul];
    }
    __syncthreads();
#pragma unroll 2
    for (int uhr = 0; uhr < 64; ++uhr) {
      float4 a0 = *(const float4*)&rolled[uhr][tt*4];
      float4 a1 = *(const float4*)&rolled[uhr][tt*4 + 64];
      float4 w0 = *(const float4*)&wo_lds[uhr][ff*4];
      float4 w1 = *(const float4*)&wo_lds[uhr][ff*4 + 64];
      float av[8] = {a0.x,a0.y,a0.z,a0.w, a1.x,a1.y,a1.z,a1.w};
      float wv_[8] = {w0.x,w0.y,w0.z,w0.w, w1.x,w1.y,w1.z,w1.w};
#pragma unroll
      for (int ti = 0; ti < 8; ++ti)
#pragma unroll
        for (int fj = 0; fj < 8; ++fj)
          acc[ti][fj] = fmaf(av[ti], wv_[fj], acc[ti][fj]);
    }
  }

  const size_t NP = (size_t)BT * EE;
#pragma unroll
  for (int ia = 0; ia < 2; ++ia)
#pragma unroll
    for (int i = 0; i < 4; ++i) {
      size_t t = (size_t)mt*128 + ia*64 + tt*4 + i;
#pragma unroll
      for (int jb = 0; jb < 2; ++jb) {
        float4 o = make_float4(acc[ia*4+i][jb*4+0], acc[ia*4+i][jb*4+1],
                               acc[ia*4+i][jb*4+2], acc[ia*4+i][jb*4+3]);
        *(float4*)&partial[ks*NP + t*EE + jb*64 + ff*4] = o;
      }
    }
}

// ---------------------------------------------------------------------------
// Stage 4b: out = sum_ks partial + bo
// ---------------------------------------------------------------------------
__global__ __launch_bounds__(256)
void reduce_kernel(const float* __restrict__ partial, const float* __restrict__ bo,
                   float* __restrict__ out)
{
  const size_t NP = (size_t)BT * EE;
  int idx4 = blockIdx.x*256 + threadIdx.x;     // 0 .. 524287
  size_t i = (size_t)idx4 * 4;
  int f4 = (idx4 & 31) * 4;
  float4 s0 = *(const float4*)&partial[i];
  float4 s1 = *(const float4*)&partial[NP + i];
  float4 s2 = *(const float4*)&partial[2*NP + i];
  float4 s3 = *(const float4*)&partial[3*NP + i];
  float4 bb = *(const float4*)&bo[f4];
  float4 o = make_float4(s0.x+s1.x+s2.x+s3.x+bb.x, s0.y+s1.y+s2.y+s3.y+bb.y,
                         s0.z+s1.z+s2.z+s3.z+bb.z, s0.w+s1.w+s2.w+s3.w+bb.w);
  *(float4*)&out[i] = o;
}

// ---------------------------------------------------------------------------
extern "C" void kernel_launch(void* const* d_in, const int* in_sizes, int n_in,
                              void* d_out, int out_size, void* d_ws, size_t ws_size,
                              hipStream_t stream) {
  (void)in_sizes; (void)n_in; (void)out_size; (void)ws_size;
  const float* hs = (const float*)d_in[0];
  const float* wq = (const float*)d_in[1];
  const float* bq = (const float*)d_in[2];
  const float* wk = (const float*)d_in[3];
  const float* bk = (const float*)d_in[4];
  const float* wv = (const float*)d_in[5];
  const float* bv = (const float*)d_in[6];
  const float* wo = (const float*)d_in[7];
  const float* bo = (const float*)d_in[8];
  float* out = (float*)d_out;

  // ws layout (floats): q_t | k_t | v_t (8.39M each) | ac (2.10M) | delay | wgt
  // overlays: hs_T (2.10M) shares ac's slot (dead before fft writes ac);
  //           partial (8.39M) shares q_t's slot (dead after fft).
  const size_t NQ = (size_t)BB * UHN * TSEQ;    // 8,388,608
  float* q_t = (float*)d_ws;
  float* k_t = q_t + NQ;
  float* v_t = k_t + NQ;
  float* ac  = v_t + NQ;
  int*   delay = (int*)(ac + (size_t)BB*EE*TSEQ);
  float* wgt   = (float*)(delay + BB*EE);
  float* hs_T    = ac;       // [128][16384], dead before fftcorr writes ac
  float* partial = q_t;      // [4][16384][128], q_t dead after fftcorr

  transpose_hs<<<dim3(256, 2), 256, 0, stream>>>(hs, hs_T);
  proj_kernel<<<dim3(4, 128, 3), 256, 0, stream>>>(hs_T, wq, bq, wk, bk, wv, bv,
                                                   q_t, k_t, v_t);
  fftcorr_kernel<<<dim3(1024), 256, 0, stream>>>(q_t, k_t, ac);
  topk_kernel<<<dim3(1024), 256, 0, stream>>>(ac, delay, wgt);
  outp_kernel<<<dim3(128, 4), 256, 0, stream>>>(v_t, delay, wgt, wo, partial);
  reduce_kernel<<<dim3(2048), 256, 0, stream>>>(partial, bo, out);
}

// Round 3
// 141.925 us; speedup vs baseline: 2.6029x; 1.4834x over previous
//
#include <hip/hip_runtime.h>
#include <math.h>

#define TSEQ 2048
#define BB 8
#define EE 128
#define HH 4
#define UHN 512           // E*H
#define KTOP 22           // int(3*ln(2048))
#define BT (BB*TSEQ)      // 16384
#define PITCH 76          // LDS row pitch in f16 (152B: 8B aligned, low conflict)

typedef _Float16 f16;
typedef f16 f16x2 __attribute__((ext_vector_type(2)));
typedef f16 f16x4 __attribute__((ext_vector_type(4)));
typedef f16 f16x8 __attribute__((ext_vector_type(8)));
typedef float f32x4 __attribute__((ext_vector_type(4)));

__device__ __forceinline__ float2 cmul(float2 a, float2 b) {
  return make_float2(a.x*b.x - a.y*b.y, a.x*b.y + a.y*b.x);
}

// A/B fragment for mfma_f32_16x16x32_f16: lane holds row/col = lane&15,
// k = 16*(e>>2) + 4*((lane>>4)&3) + (e&3). Load as two b64 at [k, k+16].
__device__ __forceinline__ f16x8 ld_frag(const f16* p) {
  f16x4 lo = *(const f16x4*)(p);
  f16x4 hi = *(const f16x4*)(p + 16);
  return __builtin_shufflevector(lo, hi, 0, 1, 2, 3, 4, 5, 6, 7);
}

// ---------------------------------------------------------------------------
// Stage 1: q/k/v = hs @ W + b via f16-split MFMA (Ah*Bh + Ah*Bl + Al*Bh),
// output transposed [b][uh][t]. A-operand = W^T (m=uh), B-operand = hs (n=t).
// Block: 128 uh x 128 t, K=128 in 2 chunks of 64. 4 waves, each 64x64.
// grid (4 uh-tiles, 128 bt-tiles, 3 weights), 256 threads
// ---------------------------------------------------------------------------
__global__ __launch_bounds__(256, 2)
void proj_mfma(const float* __restrict__ hs,
               const float* __restrict__ wq, const float* __restrict__ bq,
               const float* __restrict__ wk, const float* __restrict__ bk,
               const float* __restrict__ wv, const float* __restrict__ bv,
               float* __restrict__ q_t, float* __restrict__ k_t, float* __restrict__ v_t)
{
  __shared__ f16 Ah[128*PITCH];   // W^T hi: [uh_local][k_local]
  __shared__ f16 Al[128*PITCH];   // W^T lo
  __shared__ f16 Bh[128*PITCH];   // hs hi:  [t_local][k_local]
  __shared__ f16 Bl[128*PITCH];   // hs lo

  const float* W; const float* bias; float* outp;
  if (blockIdx.z == 0)      { W = wq; bias = bq; outp = q_t; }
  else if (blockIdx.z == 1) { W = wk; bias = bk; outp = k_t; }
  else                      { W = wv; bias = bv; outp = v_t; }

  const int tid  = threadIdx.x;
  const int lane = tid & 63, wid = tid >> 6;
  const int wm = wid >> 1, wn = wid & 1;        // wave grid 2x2, tile 64x64
  const int ln15 = lane & 15, g = lane >> 4;    // g in 0..3
  const int uh0 = blockIdx.x * 128;
  const int bt0 = blockIdx.y * 128;

  f32x4 acc[4][4] = {};

  for (int kc = 0; kc < 2; ++kc) {
    const int k0 = kc * 64;
    __syncthreads();
    // stage W chunk [64 k][128 uh] -> Ah/Al [uh][k] (transposed, f16 split)
#pragma unroll
    for (int r = 0; r < 16; ++r) {
      int idx = tid + 256*r;              // 4096 = 128 uh * 32 k-pairs
      int u = idx & 127, kp = idx >> 7;   // kp 0..31
      float w0 = W[(size_t)(k0 + 2*kp    )*UHN + uh0 + u];
      float w1 = W[(size_t)(k0 + 2*kp + 1)*UHN + uh0 + u];
      f16 h0 = (f16)w0, h1 = (f16)w1;
      f16 l0 = (f16)(w0 - (float)h0), l1 = (f16)(w1 - (float)h1);
      *(f16x2*)&Ah[u*PITCH + 2*kp] = (f16x2){h0, h1};
      *(f16x2*)&Al[u*PITCH + 2*kp] = (f16x2){l0, l1};
    }
    // stage hs chunk [128 t][64 k] -> Bh/Bl [t][k]
#pragma unroll
    for (int r = 0; r < 8; ++r) {
      int idx4 = tid + 256*r;             // 2048 float4 = 128 t * 16
      int tl = idx4 >> 4, kq = idx4 & 15;
      float4 hv = *(const float4*)&hs[(size_t)(bt0 + tl)*EE + k0 + 4*kq];
      f16 h0 = (f16)hv.x, h1 = (f16)hv.y, h2 = (f16)hv.z, h3 = (f16)hv.w;
      *(f16x4*)&Bh[tl*PITCH + 4*kq] = (f16x4){h0, h1, h2, h3};
      *(f16x4*)&Bl[tl*PITCH + 4*kq] =
        (f16x4){(f16)(hv.x - (float)h0), (f16)(hv.y - (float)h1),
                (f16)(hv.z - (float)h2), (f16)(hv.w - (float)h3)};
    }
    __syncthreads();
#pragma unroll
    for (int ks = 0; ks < 2; ++ks) {      // two K=32 steps per chunk
      const int kb = ks*32 + 4*g;
      f16x8 a_h[4], a_l[4], b_h[4], b_l[4];
#pragma unroll
      for (int mf = 0; mf < 4; ++mf) {
        int off = (wm*64 + mf*16 + ln15)*PITCH + kb;
        a_h[mf] = ld_frag(&Ah[off]);
        a_l[mf] = ld_frag(&Al[off]);
      }
#pragma unroll
      for (int nf = 0; nf < 4; ++nf) {
        int off = (wn*64 + nf*16 + ln15)*PITCH + kb;
        b_h[nf] = ld_frag(&Bh[off]);
        b_l[nf] = ld_frag(&Bl[off]);
      }
#pragma unroll
      for (int mf = 0; mf < 4; ++mf)
#pragma unroll
        for (int nf = 0; nf < 4; ++nf) {
          acc[mf][nf] = __builtin_amdgcn_mfma_f32_16x16x32_f16(a_h[mf], b_h[nf], acc[mf][nf], 0, 0, 0);
          acc[mf][nf] = __builtin_amdgcn_mfma_f32_16x16x32_f16(a_h[mf], b_l[nf], acc[mf][nf], 0, 0, 0);
          acc[mf][nf] = __builtin_amdgcn_mfma_f32_16x16x32_f16(a_l[mf], b_h[nf], acc[mf][nf], 0, 0, 0);
        }
    }
  }

  // epilogue: D row (uh) = (lane>>4)*4 + reg, col (t) = lane&15  [m89-verified]
  const int b = bt0 >> 11, tb = bt0 & (TSEQ - 1);
#pragma unroll
  for (int mf = 0; mf < 4; ++mf) {
    int uhb = uh0 + wm*64 + mf*16 + g*4;
    f32x4 bias4 = *(const f32x4*)&bias[uhb];
#pragma unroll
    for (int r = 0; r < 4; ++r) {
      size_t rowbase = ((size_t)(b*UHN + uhb + r))*TSEQ + tb;
#pragma unroll
      for (int nf = 0; nf < 4; ++nf) {
        int t = wn*64 + nf*16 + ln15;
        outp[rowbase + t] = acc[mf][nf][r] + bias4[r];
      }
    }
  }
}

// ---------------------------------------------------------------------------
// Stage 2: per (b,u): ac = (1/(T*H)) IDFT( sum_h Q_h conj(K_h) )
// packed: one complex FFT of z = q + i*k per h; unpack+multiply in bitrev
// order via partner pp = brev11(N - brev11(p)).
// ---------------------------------------------------------------------------
__device__ __forceinline__ int brev11(int x) { return (int)(__brev((unsigned)x) >> 21); }

__global__ __launch_bounds__(256)
void fftcorr_kernel(const float* __restrict__ q_t, const float* __restrict__ k_t,
                    float* __restrict__ ac)
{
  __shared__ float2 bufZ[TSEQ];
  __shared__ float2 Sbuf[TSEQ];
  __shared__ float2 tw[TSEQ/2];    // tw[j] = e^{-2*pi*i*j/2048}

  const int tid = threadIdx.x;
  const int bu  = blockIdx.x;      // b*128 + u

#pragma unroll
  for (int r = 0; r < 4; ++r) {
    int j = tid + 256*r;
    float ang = -6.2831853071795864769f * (float)j / (float)TSEQ;
    float s, c;
    sincosf(ang, &s, &c);
    tw[j] = make_float2(c, s);
  }

  for (int h = 0; h < HH; ++h) {
    const float* qp = q_t + ((size_t)bu*HH + h)*TSEQ;
    const float* kp = k_t + ((size_t)bu*HH + h)*TSEQ;
    __syncthreads();               // prior product reads done before overwrite
#pragma unroll
    for (int r = 0; r < 8; ++r) {
      int i = tid + 256*r;
      bufZ[i] = make_float2(qp[i], kp[i]);
    }
    // forward DIF: natural -> bit-reversed
    int half = 1024, tws = 1;
    for (int st = 0; st < 11; ++st) {
      __syncthreads();
#pragma unroll
      for (int r = 0; r < 4; ++r) {
        int i = tid + 256*r;                 // butterfly id 0..1023
        int j = i & (half - 1);
        int i0 = ((i - j) << 1) + j;
        int i1 = i0 + half;
        float2 w = tw[j * tws];
        float2 a = bufZ[i0], b2 = bufZ[i1];
        bufZ[i0] = make_float2(a.x + b2.x, a.y + b2.y);
        float2 d = make_float2(a.x - b2.x, a.y - b2.y);
        bufZ[i1] = cmul(d, w);
      }
      half >>= 1; tws <<= 1;
    }
    __syncthreads();
    // unpack Q,K from packed Z and accumulate S += Q * conj(K), in bitrev order
#pragma unroll
    for (int r = 0; r < 8; ++r) {
      int p = tid + 256*r;
      int kfreq = brev11(p);
      int pp = brev11((TSEQ - kfreq) & (TSEQ - 1));
      float2 A  = bufZ[p];
      float2 Zp = bufZ[pp];
      float re = 0.5f  * (Zp.x*A.y + Zp.y*A.x);
      float im = 0.25f * ((A.x*A.x + A.y*A.y) - (Zp.x*Zp.x + Zp.y*Zp.y));
      if (h == 0) Sbuf[p] = make_float2(re, im);
      else { Sbuf[p].x += re; Sbuf[p].y += im; }
    }
  }

  // inverse DIT (conjugate twiddles), bitrev input -> natural output
  {
    int half = 1, tws = 1024;
    for (int st = 0; st < 11; ++st) {
      __syncthreads();
#pragma unroll
      for (int r = 0; r < 4; ++r) {
        int i = tid + 256*r;
        int j = i & (half - 1);
        int i0 = ((i - j) << 1) + j;
        int i1 = i0 + half;
        float2 w = tw[j * tws]; w.y = -w.y;
        float2 a = Sbuf[i0], b2 = Sbuf[i1];
        float2 t = cmul(b2, w);
        Sbuf[i0] = make_float2(a.x + t.x, a.y + t.y);
        Sbuf[i1] = make_float2(a.x - t.x, a.y - t.y);
      }
      half <<= 1; tws >>= 1;
    }
  }
  __syncthreads();

  const float scale = 1.0f / (float)(TSEQ * HH);
#pragma unroll
  for (int r = 0; r < 8; ++r) {
    int i = tid + 256*r;
    ac[(size_t)bu*TSEQ + i] = Sbuf[i].x * scale;
  }
}

// ---------------------------------------------------------------------------
// Stage 3: top-22 per (b,u); keep idx[21], softmax(vals)[21]
// ---------------------------------------------------------------------------
__global__ __launch_bounds__(256)
void topk_kernel(const float* __restrict__ ac, int* __restrict__ delay,
                 float* __restrict__ wgt)
{
  __shared__ float v[TSEQ];
  __shared__ float rv[4];
  __shared__ int   ri[4];

  const int tid = threadIdx.x;
  const int bu  = blockIdx.x;

#pragma unroll
  for (int r = 0; r < 8; ++r) {
    int i = tid + 256*r;
    v[i] = ac[(size_t)bu*TSEQ + i];
  }

  float m0 = 0.f, ssum = 0.f;   // only thread 0's copies matter
  for (int it = 0; it < KTOP; ++it) {
    __syncthreads();
    float best = -3.4e38f; int bi = 0;
#pragma unroll
    for (int r = 0; r < 8; ++r) {
      int i = tid + 256*r;      // increasing -> earliest idx kept on ties
      float x = v[i];
      if (x > best) { best = x; bi = i; }
    }
#pragma unroll
    for (int off = 32; off > 0; off >>= 1) {
      float ob = __shfl_down(best, off);
      int   oi = __shfl_down(bi, off);
      if (ob > best || (ob == best && oi < bi)) { best = ob; bi = oi; }
    }
    if ((tid & 63) == 0) { rv[tid >> 6] = best; ri[tid >> 6] = bi; }
    __syncthreads();
    if (tid == 0) {
      float gb = rv[0]; int gi = ri[0];
      for (int w2 = 1; w2 < 4; ++w2)
        if (rv[w2] > gb || (rv[w2] == gb && ri[w2] < gi)) { gb = rv[w2]; gi = ri[w2]; }
      v[gi] = -3.4e38f;
      if (it == 0) m0 = gb;
      ssum += expf(gb - m0);
      if (it == KTOP - 1) {
        delay[bu] = gi;
        wgt[bu]   = expf(gb - m0) / ssum;
      }
    }
  }
}

// ---------------------------------------------------------------------------
// Stage 4: out[bt][f] = sum_uh rolled_v[t][uh] * wo[uh][f] + bo, f16 MFMA
// (single-pass f16: selection not involved; error << threshold)
// Block 64 t x 64 f, K=512 in 8 chunks of 64. grid (256 bt-tiles, 2 f-tiles)
// ---------------------------------------------------------------------------
__global__ __launch_bounds__(256)
void out_mfma(const float* __restrict__ v_t, const int* __restrict__ delay,
              const float* __restrict__ wgt, const float* __restrict__ wo,
              const float* __restrict__ bo, float* __restrict__ out)
{
  __shared__ f16 Af[64*PITCH];   // rolled [t_local][uh_local]
  __shared__ f16 Bf[64*PITCH];   // wo^T   [f_local][uh_local]
  __shared__ int   dly[EE];
  __shared__ float wg[EE];

  const int tid  = threadIdx.x;
  const int lane = tid & 63, wid = tid >> 6;
  const int wm = wid >> 1, wn = wid & 1;     // wave tile 32t x 32f
  const int ln15 = lane & 15, g = lane >> 4;
  const int t0g = blockIdx.x * 64;           // global bt base (64 | 2048)
  const int f0  = blockIdx.y * 64;
  const int b = t0g >> 11, t0 = t0g & (TSEQ - 1);

  if (tid < EE) { dly[tid] = delay[b*EE + tid]; wg[tid] = wgt[b*EE + tid]; }

  f32x4 acc[2][2] = {};

  for (int c = 0; c < 8; ++c) {
    const int uh0 = c * 64;
    __syncthreads();   // also covers dly/wg visibility on c==0
    // stage rolled v: [64 t][64 uh]
#pragma unroll
    for (int r = 0; r < 16; ++r) {
      int idx = tid + 256*r;           // 4096
      int tl = idx & 63, ul = idx >> 6;
      int u = (uh0 + ul) >> 2;
      float x = v_t[((size_t)(b*UHN + uh0 + ul))*TSEQ + ((t0 + tl + dly[u]) & (TSEQ-1))]
                * wg[u];
      Af[tl*PITCH + ul] = (f16)x;
    }
    // stage wo^T: [64 f][64 uh]
#pragma unroll
    for (int r = 0; r < 16; ++r) {
      int idx = tid + 256*r;
      int fl = idx & 63, ul = idx >> 6;
      Bf[fl*PITCH + ul] = (f16)wo[(size_t)(uh0 + ul)*EE + f0 + fl];
    }
    __syncthreads();
#pragma unroll
    for (int ks = 0; ks < 2; ++ks) {
      const int kb = ks*32 + 4*g;
      f16x8 av[2], bv[2];
#pragma unroll
      for (int mf = 0; mf < 2; ++mf)
        av[mf] = ld_frag(&Af[(wm*32 + mf*16 + ln15)*PITCH + kb]);
#pragma unroll
      for (int nf = 0; nf < 2; ++nf)
        bv[nf] = ld_frag(&Bf[(wn*32 + nf*16 + ln15)*PITCH + kb]);
#pragma unroll
      for (int mf = 0; mf < 2; ++mf)
#pragma unroll
        for (int nf = 0; nf < 2; ++nf)
          acc[mf][nf] = __builtin_amdgcn_mfma_f32_16x16x32_f16(av[mf], bv[nf], acc[mf][nf], 0, 0, 0);
    }
  }

  // epilogue: rows = t, cols = f
#pragma unroll
  for (int mf = 0; mf < 2; ++mf)
#pragma unroll
    for (int r = 0; r < 4; ++r) {
      int bt = t0g + wm*32 + mf*16 + g*4 + r;
#pragma unroll
      for (int nf = 0; nf < 2; ++nf) {
        int f = f0 + wn*32 + nf*16 + ln15;
        out[(size_t)bt*EE + f] = acc[mf][nf][r] + bo[f];
      }
    }
}

// ---------------------------------------------------------------------------
extern "C" void kernel_launch(void* const* d_in, const int* in_sizes, int n_in,
                              void* d_out, int out_size, void* d_ws, size_t ws_size,
                              hipStream_t stream) {
  (void)in_sizes; (void)n_in; (void)out_size; (void)ws_size;
  const float* hs = (const float*)d_in[0];
  const float* wq = (const float*)d_in[1];
  const float* bq = (const float*)d_in[2];
  const float* wk = (const float*)d_in[3];
  const float* bk = (const float*)d_in[4];
  const float* wv = (const float*)d_in[5];
  const float* bv = (const float*)d_in[6];
  const float* wo = (const float*)d_in[7];
  const float* bo = (const float*)d_in[8];
  float* out = (float*)d_out;

  // ws (floats): q_t | k_t | v_t (8.39M each) | ac (2.10M) | delay | wgt
  const size_t NQ = (size_t)BB * UHN * TSEQ;    // 8,388,608
  float* q_t = (float*)d_ws;
  float* k_t = q_t + NQ;
  float* v_t = k_t + NQ;
  float* ac  = v_t + NQ;
  int*   delay = (int*)(ac + (size_t)BB*EE*TSEQ);
  float* wgt   = (float*)(delay + BB*EE);

  proj_mfma<<<dim3(4, 128, 3), 256, 0, stream>>>(hs, wq, bq, wk, bk, wv, bv,
                                                 q_t, k_t, v_t);
  fftcorr_kernel<<<dim3(1024), 256, 0, stream>>>(q_t, k_t, ac);
  topk_kernel<<<dim3(1024), 256, 0, stream>>>(ac, delay, wgt);
  out_mfma<<<dim3(256, 2), 256, 0, stream>>>(v_t, delay, wgt, wo, bo, out);
}

// Round 4
// 116.649 us; speedup vs baseline: 3.1669x; 1.2167x over previous
//
#include <hip/hip_runtime.h>
#include <math.h>

#define TSEQ 2048
#define BB 8
#define EE 128
#define HH 4
#define UHN 512           // E*H
#define KTOP 22           // int(3*ln(2048))
#define BT (BB*TSEQ)      // 16384
#define PITCH 76          // LDS row pitch in f16 (152B: 8B aligned, low conflict)

typedef _Float16 f16;
typedef f16 f16x2 __attribute__((ext_vector_type(2)));
typedef f16 f16x4 __attribute__((ext_vector_type(4)));
typedef f16 f16x8 __attribute__((ext_vector_type(8)));
typedef float f32x4 __attribute__((ext_vector_type(4)));

__device__ __forceinline__ float2 cmul(float2 a, float2 b) {
  return make_float2(a.x*b.x - a.y*b.y, a.x*b.y + a.y*b.x);
}
__device__ __forceinline__ float2 cadd(float2 a, float2 b) {
  return make_float2(a.x + b.x, a.y + b.y);
}
__device__ __forceinline__ float2 csub(float2 a, float2 b) {
  return make_float2(a.x - b.x, a.y - b.y);
}

// A/B fragment for mfma_f32_16x16x32_f16: lane holds row/col = lane&15,
// k = 16*(e>>2) + 4*((lane>>4)&3) + (e&3). Load as two b64 at [k, k+16].
__device__ __forceinline__ f16x8 ld_frag(const f16* p) {
  f16x4 lo = *(const f16x4*)(p);
  f16x4 hi = *(const f16x4*)(p + 16);
  return __builtin_shufflevector(lo, hi, 0, 1, 2, 3, 4, 5, 6, 7);
}

// ---------------------------------------------------------------------------
// Stage 1: q/k/v = hs @ W + b via f16-split MFMA (Ah*Bh + Ah*Bl + Al*Bh),
// output transposed [b][uh][t]. (unchanged from round 3)
// ---------------------------------------------------------------------------
__global__ __launch_bounds__(256, 2)
void proj_mfma(const float* __restrict__ hs,
               const float* __restrict__ wq, const float* __restrict__ bq,
               const float* __restrict__ wk, const float* __restrict__ bk,
               const float* __restrict__ wv, const float* __restrict__ bv,
               float* __restrict__ q_t, float* __restrict__ k_t, float* __restrict__ v_t)
{
  __shared__ f16 Ah[128*PITCH];
  __shared__ f16 Al[128*PITCH];
  __shared__ f16 Bh[128*PITCH];
  __shared__ f16 Bl[128*PITCH];

  const float* W; const float* bias; float* outp;
  if (blockIdx.z == 0)      { W = wq; bias = bq; outp = q_t; }
  else if (blockIdx.z == 1) { W = wk; bias = bk; outp = k_t; }
  else                      { W = wv; bias = bv; outp = v_t; }

  const int tid  = threadIdx.x;
  const int lane = tid & 63, wid = tid >> 6;
  const int wm = wid >> 1, wn = wid & 1;
  const int ln15 = lane & 15, g = lane >> 4;
  const int uh0 = blockIdx.x * 128;
  const int bt0 = blockIdx.y * 128;

  f32x4 acc[4][4] = {};

  for (int kc = 0; kc < 2; ++kc) {
    const int k0 = kc * 64;
    __syncthreads();
#pragma unroll
    for (int r = 0; r < 16; ++r) {
      int idx = tid + 256*r;
      int u = idx & 127, kp = idx >> 7;
      float w0 = W[(size_t)(k0 + 2*kp    )*UHN + uh0 + u];
      float w1 = W[(size_t)(k0 + 2*kp + 1)*UHN + uh0 + u];
      f16 h0 = (f16)w0, h1 = (f16)w1;
      f16 l0 = (f16)(w0 - (float)h0), l1 = (f16)(w1 - (float)h1);
      *(f16x2*)&Ah[u*PITCH + 2*kp] = (f16x2){h0, h1};
      *(f16x2*)&Al[u*PITCH + 2*kp] = (f16x2){l0, l1};
    }
#pragma unroll
    for (int r = 0; r < 8; ++r) {
      int idx4 = tid + 256*r;
      int tl = idx4 >> 4, kq = idx4 & 15;
      float4 hv = *(const float4*)&hs[(size_t)(bt0 + tl)*EE + k0 + 4*kq];
      f16 h0 = (f16)hv.x, h1 = (f16)hv.y, h2 = (f16)hv.z, h3 = (f16)hv.w;
      *(f16x4*)&Bh[tl*PITCH + 4*kq] = (f16x4){h0, h1, h2, h3};
      *(f16x4*)&Bl[tl*PITCH + 4*kq] =
        (f16x4){(f16)(hv.x - (float)h0), (f16)(hv.y - (float)h1),
                (f16)(hv.z - (float)h2), (f16)(hv.w - (float)h3)};
    }
    __syncthreads();
#pragma unroll
    for (int ks = 0; ks < 2; ++ks) {
      const int kb = ks*32 + 4*g;
      f16x8 a_h[4], a_l[4], b_h[4], b_l[4];
#pragma unroll
      for (int mf = 0; mf < 4; ++mf) {
        int off = (wm*64 + mf*16 + ln15)*PITCH + kb;
        a_h[mf] = ld_frag(&Ah[off]);
        a_l[mf] = ld_frag(&Al[off]);
      }
#pragma unroll
      for (int nf = 0; nf < 4; ++nf) {
        int off = (wn*64 + nf*16 + ln15)*PITCH + kb;
        b_h[nf] = ld_frag(&Bh[off]);
        b_l[nf] = ld_frag(&Bl[off]);
      }
#pragma unroll
      for (int mf = 0; mf < 4; ++mf)
#pragma unroll
        for (int nf = 0; nf < 4; ++nf) {
          acc[mf][nf] = __builtin_amdgcn_mfma_f32_16x16x32_f16(a_h[mf], b_h[nf], acc[mf][nf], 0, 0, 0);
          acc[mf][nf] = __builtin_amdgcn_mfma_f32_16x16x32_f16(a_h[mf], b_l[nf], acc[mf][nf], 0, 0, 0);
          acc[mf][nf] = __builtin_amdgcn_mfma_f32_16x16x32_f16(a_l[mf], b_h[nf], acc[mf][nf], 0, 0, 0);
        }
    }
  }

  const int b = bt0 >> 11, tb = bt0 & (TSEQ - 1);
#pragma unroll
  for (int mf = 0; mf < 4; ++mf) {
    int uhb = uh0 + wm*64 + mf*16 + g*4;
    f32x4 bias4 = *(const f32x4*)&bias[uhb];
#pragma unroll
    for (int r = 0; r < 4; ++r) {
      size_t rowbase = ((size_t)(b*UHN + uhb + r))*TSEQ + tb;
#pragma unroll
      for (int nf = 0; nf < 4; ++nf) {
        int t = wn*64 + nf*16 + ln15;
        outp[rowbase + t] = acc[mf][nf][r] + bias4[r];
      }
    }
  }
}

// ---------------------------------------------------------------------------
// Stage 2: radix-8 FFT correlation.
// Forward DIF radices [8,8,8,4] (natural -> digit-reversed), product+h-sum in
// registers at digit-reversed positions, inverse DIT [4,8,8,8] -> natural.
// Position p = (d1:3|d2:3|d3:3|d4:2) holds frequency f = d1+8*d2+64*d3+512*d4.
// LDS: Z[2112] padded (g + g>>5), tw tables 292 entries. ~19.5 KB.
// ---------------------------------------------------------------------------
#define ZPAD(g) ((g) + ((g) >> 5))

template<int SGN>  // a + SGN*i*b
__device__ __forceinline__ float2 addim(float2 a, float2 b) {
  return (SGN < 0) ? make_float2(a.x + b.y, a.y - b.x)
                   : make_float2(a.x - b.y, a.y + b.x);
}
template<int SGN>  // a - SGN*i*b
__device__ __forceinline__ float2 subim(float2 a, float2 b) {
  return (SGN < 0) ? make_float2(a.x - b.y, a.y + b.x)
                   : make_float2(a.x + b.y, a.y - b.x);
}

// 8-point DFT, Y_s = sum_t u_t * e^{SGN*2pi*i*st/8}
template<int SGN>
__device__ __forceinline__ void dft8(const float2* u, float2* y) {
  const float r2 = 0.70710678118654752440f;
  float2 a0 = cadd(u[0], u[4]), a1 = cadd(u[1], u[5]);
  float2 a2 = cadd(u[2], u[6]), a3 = cadd(u[3], u[7]);
  float2 b0 = csub(u[0], u[4]), b1 = csub(u[1], u[5]);
  float2 b2 = csub(u[2], u[6]), b3 = csub(u[3], u[7]);
  // b1 *= (1 + SGN i)*r2 ; b2 *= SGN i ; b3 *= SGN i * (1 + SGN i)*r2
  float2 t1 = (SGN < 0) ? make_float2(r2*(b1.x + b1.y), r2*(b1.y - b1.x))
                        : make_float2(r2*(b1.x - b1.y), r2*(b1.y + b1.x));
  float2 t2 = (SGN < 0) ? make_float2(b2.y, -b2.x) : make_float2(-b2.y, b2.x);
  float2 e  = (SGN < 0) ? make_float2(r2*(b3.x + b3.y), r2*(b3.y - b3.x))
                        : make_float2(r2*(b3.x - b3.y), r2*(b3.y + b3.x));
  float2 t3 = (SGN < 0) ? make_float2(e.y, -e.x) : make_float2(-e.y, e.x);
  {
    float2 c0 = cadd(a0, a2), c1 = csub(a0, a2);
    float2 c2 = cadd(a1, a3), c3 = csub(a1, a3);
    y[0] = cadd(c0, c2); y[4] = csub(c0, c2);
    y[2] = addim<SGN>(c1, c3); y[6] = subim<SGN>(c1, c3);
  }
  {
    float2 c0 = cadd(b0, t2), c1 = csub(b0, t2);
    float2 c2 = cadd(t1, t3), c3 = csub(t1, t3);
    y[1] = cadd(c0, c2); y[5] = csub(c0, c2);
    y[3] = addim<SGN>(c1, c3); y[7] = subim<SGN>(c1, c3);
  }
}

// forward DIF radix-8: butterfly then multiply outputs by w1^s
__device__ __forceinline__ void fwd_radix8(float2* Z, float2 w1, int base, int eighth) {
  float2 u[8];
#pragma unroll
  for (int t = 0; t < 8; ++t) u[t] = Z[ZPAD(base + eighth*t)];
  float2 y[8];
  dft8<-1>(u, y);
  Z[ZPAD(base)] = y[0];
  float2 w = w1;
  Z[ZPAD(base + eighth)] = cmul(y[1], w);
#pragma unroll
  for (int s = 2; s < 8; ++s) {
    w = cmul(w, w1);
    Z[ZPAD(base + eighth*s)] = cmul(y[s], w);
  }
}

// inverse DIT radix-8: multiply inputs by w1c^t (w1c pre-conjugated), then idft8
__device__ __forceinline__ void inv_radix8(float2* Z, float2 w1c, int base, int eighth) {
  float2 u[8];
#pragma unroll
  for (int t = 0; t < 8; ++t) u[t] = Z[ZPAD(base + eighth*t)];
  u[1] = cmul(u[1], w1c);
  float2 w = w1c;
#pragma unroll
  for (int t = 2; t < 8; ++t) {
    w = cmul(w, w1c);
    u[t] = cmul(u[t], w);
  }
  float2 y[8];
  dft8<1>(u, y);
#pragma unroll
  for (int s = 0; s < 8; ++s) Z[ZPAD(base + eighth*s)] = y[s];
}

template<int SGN>
__device__ __forceinline__ void radix4_stage(float2* Z, int base) {
  float2 v0 = Z[ZPAD(base)], v1 = Z[ZPAD(base+1)];
  float2 v2 = Z[ZPAD(base+2)], v3 = Z[ZPAD(base+3)];
  float2 c0 = cadd(v0, v2), c1 = csub(v0, v2);
  float2 c2 = cadd(v1, v3), c3 = csub(v1, v3);
  Z[ZPAD(base)]   = cadd(c0, c2);
  Z[ZPAD(base+1)] = addim<SGN>(c1, c3);
  Z[ZPAD(base+2)] = csub(c0, c2);
  Z[ZPAD(base+3)] = subim<SGN>(c1, c3);
}

__global__ __launch_bounds__(256)
void fftcorr_kernel(const float* __restrict__ q_t, const float* __restrict__ k_t,
                    float* __restrict__ ac)
{
  __shared__ float2 Z[2112];       // 2048 + pad every 32
  __shared__ float2 twl[292];      // tw1[256]: W_2048^j | tw2[32]: W_256^j | tw3[4]: W_32^j

  const int tid = threadIdx.x;
  const int bu  = blockIdx.x;

  for (int idx = tid; idx < 292; idx += 256) {
    float ang;
    if (idx < 256)      ang = -6.2831853071795864769f * (float)idx / 2048.0f;
    else if (idx < 288) ang = -6.2831853071795864769f * (float)(idx - 256) / 256.0f;
    else                ang = -6.2831853071795864769f * (float)(idx - 288) / 32.0f;
    float s, c;
    sincosf(ang, &s, &c);
    twl[idx] = make_float2(c, s);
  }
  const float2* tw1 = twl;
  const float2* tw2 = twl + 256;
  const float2* tw3 = twl + 288;

  // partner positions for the unpack-product (digit-reversed layout)
  int pp[8];
#pragma unroll
  for (int r = 0; r < 8; ++r) {
    int p = tid + (r << 8);
    int f = ((p >> 8) & 7) | (((p >> 5) & 7) << 3) | (((p >> 2) & 7) << 6) | ((p & 3) << 9);
    int nf = (2048 - f) & 2047;
    pp[r] = ((nf & 7) << 8) | (((nf >> 3) & 7) << 5) | (((nf >> 6) & 7) << 2) | ((nf >> 9) & 3);
  }
  float2 sreg[8] = {};
  __syncthreads();

  for (int h = 0; h < HH; ++h) {
    const float* qp = q_t + ((size_t)bu*HH + h)*TSEQ;
    const float* kp = k_t + ((size_t)bu*HH + h)*TSEQ;
    // stage F1 (m=2048, eighth=256) fused with global load; z = q + i*k
    {
      float2 u[8];
#pragma unroll
      for (int t = 0; t < 8; ++t)
        u[t] = make_float2(qp[tid + 256*t], kp[tid + 256*t]);
      float2 y[8];
      dft8<-1>(u, y);
      float2 w1 = tw1[tid];
      Z[ZPAD(tid)] = y[0];
      float2 w = w1;
      Z[ZPAD(tid + 256)] = cmul(y[1], w);
#pragma unroll
      for (int s = 2; s < 8; ++s) {
        w = cmul(w, w1);
        Z[ZPAD(tid + 256*s)] = cmul(y[s], w);
      }
    }
    __syncthreads();
    // stage F2 (m=256, eighth=32)
    fwd_radix8(Z, tw2[tid & 31], ((tid >> 5) << 8) + (tid & 31), 32);
    __syncthreads();
    // stage F3 (m=32, eighth=4)
    fwd_radix8(Z, tw3[tid & 3], ((tid >> 2) << 5) + (tid & 3), 4);
    __syncthreads();
    // stage F4 (m=4, radix-4, no twiddles)
    radix4_stage<-1>(Z, 4*tid);
    radix4_stage<-1>(Z, 4*(tid + 256));
    __syncthreads();
    // S += Q * conj(K) in digit-reversed order, accumulated in registers
#pragma unroll
    for (int r = 0; r < 8; ++r) {
      int p = tid + (r << 8);
      float2 A  = Z[ZPAD(p)];
      float2 Zp = Z[ZPAD(pp[r])];
      sreg[r].x += 0.5f  * (Zp.x*A.y + Zp.y*A.x);
      sreg[r].y += 0.25f * ((A.x*A.x + A.y*A.y) - (Zp.x*Zp.x + Zp.y*Zp.y));
    }
    __syncthreads();
  }

  // inverse DIT [4,8,8,8]
#pragma unroll
  for (int r = 0; r < 8; ++r) Z[ZPAD(tid + (r << 8))] = sreg[r];
  __syncthreads();
  radix4_stage<1>(Z, 4*tid);
  radix4_stage<1>(Z, 4*(tid + 256));
  __syncthreads();
  { float2 w = tw3[tid & 3]; w.y = -w.y;
    inv_radix8(Z, w, ((tid >> 2) << 5) + (tid & 3), 4); }
  __syncthreads();
  { float2 w = tw2[tid & 31]; w.y = -w.y;
    inv_radix8(Z, w, ((tid >> 5) << 8) + (tid & 31), 32); }
  __syncthreads();
  // stage I4 (m=2048) fused with store of real part
  {
    float2 u[8];
#pragma unroll
    for (int t = 0; t < 8; ++t) u[t] = Z[ZPAD(tid + 256*t)];
    float2 w1c = tw1[tid]; w1c.y = -w1c.y;
    u[1] = cmul(u[1], w1c);
    float2 w = w1c;
#pragma unroll
    for (int t = 2; t < 8; ++t) {
      w = cmul(w, w1c);
      u[t] = cmul(u[t], w);
    }
    float2 y[8];
    dft8<1>(u, y);
    const float scale = 1.0f / (float)(TSEQ * HH);
#pragma unroll
    for (int s = 0; s < 8; ++s)
      ac[(size_t)bu*TSEQ + tid + 256*s] = y[s].x * scale;
  }
}

// ---------------------------------------------------------------------------
// Stage 3: top-22 per (b,u); keep idx[21], softmax(vals)[21] (unchanged)
// ---------------------------------------------------------------------------
__global__ __launch_bounds__(256)
void topk_kernel(const float* __restrict__ ac, int* __restrict__ delay,
                 float* __restrict__ wgt)
{
  __shared__ float v[TSEQ];
  __shared__ float rv[4];
  __shared__ int   ri[4];

  const int tid = threadIdx.x;
  const int bu  = blockIdx.x;

#pragma unroll
  for (int r = 0; r < 8; ++r) {
    int i = tid + 256*r;
    v[i] = ac[(size_t)bu*TSEQ + i];
  }

  float m0 = 0.f, ssum = 0.f;
  for (int it = 0; it < KTOP; ++it) {
    __syncthreads();
    float best = -3.4e38f; int bi = 0;
#pragma unroll
    for (int r = 0; r < 8; ++r) {
      int i = tid + 256*r;
      float x = v[i];
      if (x > best) { best = x; bi = i; }
    }
#pragma unroll
    for (int off = 32; off > 0; off >>= 1) {
      float ob = __shfl_down(best, off);
      int   oi = __shfl_down(bi, off);
      if (ob > best || (ob == best && oi < bi)) { best = ob; bi = oi; }
    }
    if ((tid & 63) == 0) { rv[tid >> 6] = best; ri[tid >> 6] = bi; }
    __syncthreads();
    if (tid == 0) {
      float gb = rv[0]; int gi = ri[0];
      for (int w2 = 1; w2 < 4; ++w2)
        if (rv[w2] > gb || (rv[w2] == gb && ri[w2] < gi)) { gb = rv[w2]; gi = ri[w2]; }
      v[gi] = -3.4e38f;
      if (it == 0) m0 = gb;
      ssum += expf(gb - m0);
      if (it == KTOP - 1) {
        delay[bu] = gi;
        wgt[bu]   = expf(gb - m0) / ssum;
      }
    }
  }
}

// ---------------------------------------------------------------------------
// Stage 4: out = rolled_v @ wo + bo, f16 MFMA (unchanged)
// ---------------------------------------------------------------------------
__global__ __launch_bounds__(256)
void out_mfma(const float* __restrict__ v_t, const int* __restrict__ delay,
              const float* __restrict__ wgt, const float* __restrict__ wo,
              const float* __restrict__ bo, float* __restrict__ out)
{
  __shared__ f16 Af[64*PITCH];
  __shared__ f16 Bf[64*PITCH];
  __shared__ int   dly[EE];
  __shared__ float wg[EE];

  const int tid  = threadIdx.x;
  const int lane = tid & 63, wid = tid >> 6;
  const int wm = wid >> 1, wn = wid & 1;
  const int ln15 = lane & 15, g = lane >> 4;
  const int t0g = blockIdx.x * 64;
  const int f0  = blockIdx.y * 64;
  const int b = t0g >> 11, t0 = t0g & (TSEQ - 1);

  if (tid < EE) { dly[tid] = delay[b*EE + tid]; wg[tid] = wgt[b*EE + tid]; }

  f32x4 acc[2][2] = {};

  for (int c = 0; c < 8; ++c) {
    const int uh0 = c * 64;
    __syncthreads();
#pragma unroll
    for (int r = 0; r < 16; ++r) {
      int idx = tid + 256*r;
      int tl = idx & 63, ul = idx >> 6;
      int u = (uh0 + ul) >> 2;
      float x = v_t[((size_t)(b*UHN + uh0 + ul))*TSEQ + ((t0 + tl + dly[u]) & (TSEQ-1))]
                * wg[u];
      Af[tl*PITCH + ul] = (f16)x;
    }
#pragma unroll
    for (int r = 0; r < 16; ++r) {
      int idx = tid + 256*r;
      int fl = idx & 63, ul = idx >> 6;
      Bf[fl*PITCH + ul] = (f16)wo[(size_t)(uh0 + ul)*EE + f0 + fl];
    }
    __syncthreads();
#pragma unroll
    for (int ks = 0; ks < 2; ++ks) {
      const int kb = ks*32 + 4*g;
      f16x8 av[2], bv[2];
#pragma unroll
      for (int mf = 0; mf < 2; ++mf)
        av[mf] = ld_frag(&Af[(wm*32 + mf*16 + ln15)*PITCH + kb]);
#pragma unroll
      for (int nf = 0; nf < 2; ++nf)
        bv[nf] = ld_frag(&Bf[(wn*32 + nf*16 + ln15)*PITCH + kb]);
#pragma unroll
      for (int mf = 0; mf < 2; ++mf)
#pragma unroll
        for (int nf = 0; nf < 2; ++nf)
          acc[mf][nf] = __builtin_amdgcn_mfma_f32_16x16x32_f16(av[mf], bv[nf], acc[mf][nf], 0, 0, 0);
    }
  }

#pragma unroll
  for (int mf = 0; mf < 2; ++mf)
#pragma unroll
    for (int r = 0; r < 4; ++r) {
      int bt = t0g + wm*32 + mf*16 + g*4 + r;
#pragma unroll
      for (int nf = 0; nf < 2; ++nf) {
        int f = f0 + wn*32 + nf*16 + ln15;
        out[(size_t)bt*EE + f] = acc[mf][nf][r] + bo[f];
      }
    }
}

// ---------------------------------------------------------------------------
extern "C" void kernel_launch(void* const* d_in, const int* in_sizes, int n_in,
                              void* d_out, int out_size, void* d_ws, size_t ws_size,
                              hipStream_t stream) {
  (void)in_sizes; (void)n_in; (void)out_size; (void)ws_size;
  const float* hs = (const float*)d_in[0];
  const float* wq = (const float*)d_in[1];
  const float* bq = (const float*)d_in[2];
  const float* wk = (const float*)d_in[3];
  const float* bk = (const float*)d_in[4];
  const float* wv = (const float*)d_in[5];
  const float* bv = (const float*)d_in[6];
  const float* wo = (const float*)d_in[7];
  const float* bo = (const float*)d_in[8];
  float* out = (float*)d_out;

  const size_t NQ = (size_t)BB * UHN * TSEQ;    // 8,388,608
  float* q_t = (float*)d_ws;
  float* k_t = q_t + NQ;
  float* v_t = k_t + NQ;
  float* ac  = v_t + NQ;
  int*   delay = (int*)(ac + (size_t)BB*EE*TSEQ);
  float* wgt   = (float*)(delay + BB*EE);

  proj_mfma<<<dim3(4, 128, 3), 256, 0, stream>>>(hs, wq, bq, wk, bk, wv, bv,
                                                 q_t, k_t, v_t);
  fftcorr_kernel<<<dim3(1024), 256, 0, stream>>>(q_t, k_t, ac);
  topk_kernel<<<dim3(1024), 256, 0, stream>>>(ac, delay, wgt);
  out_mfma<<<dim3(256, 2), 256, 0, stream>>>(v_t, delay, wgt, wo, bo, out);
}